// Round 1
// baseline (618.829 us; speedup 1.0000x reference)
//
#include <hip/hip_runtime.h>
#include <hip/hip_bf16.h>
#include <math.h>

// ---------------------------------------------------------------------------
// GCN forward, algebraically collapsed:
//   h1 = relu( dinv[d]*(sum_{e:dst=d} g[src_e] + g[d]) + b1 ),  g = (x@W1)*dinv
//   pooled = (1/N) * (sum_n w[n]*h1[n]) @ W2 + b2,
//       w[n] = dinv[n]*(wacc[n] + dinv[n]),  wacc[n] = sum_{e:src=n} dinv[dst_e]
//   out = sigmoid(pooled @ Wl + bl)
// ---------------------------------------------------------------------------

#define F_IN 256
#define H 64

// ---- K1: in-degree count ---------------------------------------------------
__global__ void count_kernel(const int* __restrict__ ei, int* __restrict__ cnt, int E) {
    int e = blockIdx.x * 256 + threadIdx.x;
    if (e < E) atomicAdd(&cnt[ei[E + e]], 1);
}

// ---- K2a: dinv -------------------------------------------------------------
__global__ void dinv_kernel(const int* __restrict__ cnt, float* __restrict__ dinv, int N) {
    int n = blockIdx.x * 256 + threadIdx.x;
    if (n < N) dinv[n] = rsqrtf(1.0f + (float)cnt[n]);
}

// ---- K2b: single-block exclusive scan -> rowstart, cursor ------------------
__global__ __launch_bounds__(1024) void scan_kernel(const int* __restrict__ cnt,
                                                    int* __restrict__ rowstart,
                                                    int* __restrict__ cursor, int N) {
    __shared__ int lds[1024];
    int t = threadIdx.x;
    int chunk = (N + 1023) / 1024;
    int lo = t * chunk;
    int hi = lo + chunk; if (hi > N) hi = N; if (lo > N) lo = N;
    int s = 0;
    for (int i = lo; i < hi; ++i) s += cnt[i];
    lds[t] = s;
    __syncthreads();
    for (int off = 1; off < 1024; off <<= 1) {
        int v = (t >= off) ? lds[t - off] : 0;
        __syncthreads();
        lds[t] += v;
        __syncthreads();
    }
    int run = lds[t] - s;   // exclusive prefix
    for (int i = lo; i < hi; ++i) {
        rowstart[i] = run; cursor[i] = run;
        run += cnt[i];
    }
    if (t == 1023) rowstart[N] = run;
}

// ---- K3: CSR scatter + wacc ------------------------------------------------
__global__ void scatter_kernel(const int* __restrict__ ei, const float* __restrict__ dinv,
                               int* __restrict__ cursor, int* __restrict__ csr_src,
                               float* __restrict__ wacc, int E) {
    int e = blockIdx.x * 256 + threadIdx.x;
    if (e < E) {
        int s = ei[e], d = ei[E + e];
        int pos = atomicAdd(&cursor[d], 1);
        csr_src[pos] = s;
        atomicAdd(&wacc[s], dinv[d]);
    }
}

// ---- K4: GEMM  g = (x @ W1) * dinv  ---------------------------------------
// 128x64 tile per block, 256 threads, 8x4 micro-tile, KT=32
#define MT 128
#define KT 32
__global__ __launch_bounds__(256) void gemm_g(const float* __restrict__ x,
                                              const float* __restrict__ W1,
                                              const float* __restrict__ dinv,
                                              float* __restrict__ g, int M) {
    __shared__ float As[KT][MT + 4];   // stored transposed; stride 132 floats (16B aligned)
    __shared__ float Bs[KT][H];
    int t = threadIdx.x;
    int rowbase = blockIdx.x * MT;
    int m0 = (t >> 4) * 8;
    int n0 = (t & 15) * 4;
    float acc[8][4] = {};
    for (int k0 = 0; k0 < F_IN; k0 += KT) {
        #pragma unroll
        for (int i = 0; i < 4; ++i) {          // stage A (transposed)
            int idx = t + i * 256;             // 0..1023
            int r  = idx >> 3;
            int kv = idx & 7;
            int row = rowbase + r;
            float4 v = make_float4(0.f, 0.f, 0.f, 0.f);
            if (row < M) v = *reinterpret_cast<const float4*>(&x[(size_t)row * F_IN + k0 + kv * 4]);
            As[kv * 4 + 0][r] = v.x; As[kv * 4 + 1][r] = v.y;
            As[kv * 4 + 2][r] = v.z; As[kv * 4 + 3][r] = v.w;
        }
        #pragma unroll
        for (int i = 0; i < 2; ++i) {          // stage B
            int idx = t + i * 256;             // 0..511
            int kk = idx >> 4;
            int cv = idx & 15;
            *reinterpret_cast<float4*>(&Bs[kk][cv * 4]) =
                *reinterpret_cast<const float4*>(&W1[(size_t)(k0 + kk) * H + cv * 4]);
        }
        __syncthreads();
        #pragma unroll
        for (int k = 0; k < KT; ++k) {
            float4 a0 = *reinterpret_cast<const float4*>(&As[k][m0]);
            float4 a1 = *reinterpret_cast<const float4*>(&As[k][m0 + 4]);
            float4 b  = *reinterpret_cast<const float4*>(&Bs[k][n0]);
            float am[8] = {a0.x, a0.y, a0.z, a0.w, a1.x, a1.y, a1.z, a1.w};
            float bn[4] = {b.x, b.y, b.z, b.w};
            #pragma unroll
            for (int mi = 0; mi < 8; ++mi)
                #pragma unroll
                for (int ni = 0; ni < 4; ++ni)
                    acc[mi][ni] += am[mi] * bn[ni];
        }
        __syncthreads();
    }
    #pragma unroll
    for (int mi = 0; mi < 8; ++mi) {
        int row = rowbase + m0 + mi;
        if (row < M) {
            float dv = dinv[row];
            float4 o = make_float4(acc[mi][0] * dv, acc[mi][1] * dv,
                                   acc[mi][2] * dv, acc[mi][3] * dv);
            *reinterpret_cast<float4*>(&g[(size_t)row * H + n0]) = o;
        }
    }
}

// ---- K6: per-node aggregation + relu + weighted reduction ------------------
__global__ __launch_bounds__(256) void agg_kernel(const float* __restrict__ g,
                                                  const int* __restrict__ rowstart,
                                                  const int* __restrict__ csr_src,
                                                  const float* __restrict__ dinv,
                                                  const float* __restrict__ wacc,
                                                  const float* __restrict__ b1,
                                                  float* __restrict__ svec, int N) {
    int lane = threadIdx.x & 63;
    int wIb  = threadIdx.x >> 6;
    int wave = blockIdx.x * 4 + wIb;
    int nWaves = gridDim.x * 4;
    float bb = b1[lane];
    float racc = 0.f;
    for (int n = wave; n < N; n += nWaves) {
        int js = rowstart[n], je = rowstart[n + 1];
        float s = 0.f;
        int j = js;
        for (; j + 3 < je; j += 4) {           // 4-way batched: break dependent-load chain
            int s0 = csr_src[j], s1 = csr_src[j + 1], s2 = csr_src[j + 2], s3 = csr_src[j + 3];
            float g0 = g[(size_t)s0 * H + lane];
            float g1 = g[(size_t)s1 * H + lane];
            float g2 = g[(size_t)s2 * H + lane];
            float g3 = g[(size_t)s3 * H + lane];
            s += (g0 + g1) + (g2 + g3);
        }
        for (; j < je; ++j) s += g[(size_t)csr_src[j] * H + lane];
        float dv = dinv[n];
        float h1 = dv * (s + g[(size_t)n * H + lane]) + bb;
        h1 = fmaxf(h1, 0.f);
        float wn = dv * (wacc[n] + dv);
        racc += wn * h1;
    }
    __shared__ float red[4][64];
    red[wIb][lane] = racc;
    __syncthreads();
    if (wIb == 0) {
        float v = red[0][lane] + red[1][lane] + red[2][lane] + red[3][lane];
        atomicAdd(&svec[lane], v);
    }
}

// ---- K7: final tiny head ---------------------------------------------------
__global__ void final_kernel(const float* __restrict__ svec,
                             const float* __restrict__ W2, const float* __restrict__ b2,
                             const float* __restrict__ Wl, const float* __restrict__ bl,
                             float* __restrict__ out, float invN) {
    __shared__ float pooled[64];
    __shared__ float sv[64];
    int t = threadIdx.x;   // 64 threads
    sv[t] = svec[t];
    __syncthreads();
    float acc = 0.f;
    for (int k = 0; k < 64; ++k) acc += sv[k] * W2[k * 64 + t];
    pooled[t] = acc * invN + b2[t];
    __syncthreads();
    if (t < 10) {
        float a = 0.f;
        for (int j = 0; j < 64; ++j) a += pooled[j] * Wl[j * 10 + t];
        a += bl[t];
        out[t] = 1.f / (1.f + expf(-a));
    }
}

// ---------------------------------------------------------------------------
extern "C" void kernel_launch(void* const* d_in, const int* in_sizes, int n_in,
                              void* d_out, int out_size, void* d_ws, size_t ws_size,
                              hipStream_t stream) {
    const float* x   = (const float*)d_in[0];
    const int*   ei  = (const int*)d_in[1];
    const float* W1  = (const float*)d_in[2];
    const float* b1  = (const float*)d_in[3];
    const float* W2  = (const float*)d_in[4];
    const float* b2  = (const float*)d_in[5];
    const float* Wl  = (const float*)d_in[6];
    const float* bl  = (const float*)d_in[7];
    float* out = (float*)d_out;

    const int N = in_sizes[0] / F_IN;
    const int E = in_sizes[1] / 2;

    // workspace carve-up (256B aligned)
    char* ws = (char*)d_ws;
    size_t off = 0;
    auto carve = [&](size_t bytes) -> char* {
        char* p = ws + off;
        off = (off + bytes + 255) & ~(size_t)255;
        return p;
    };
    int*   cnt      = (int*)  carve((size_t)N * 4);
    int*   rowstart = (int*)  carve((size_t)(N + 1) * 4);
    int*   cursor   = (int*)  carve((size_t)N * 4);
    float* dinv     = (float*)carve((size_t)N * 4);
    float* wacc     = (float*)carve((size_t)N * 4);
    float* svec     = (float*)carve(64 * 4);
    int*   csr_src  = (int*)  carve((size_t)E * 4);
    float* g        = (float*)carve((size_t)N * H * 4);
    (void)ws_size; (void)n_in; (void)out_size;

    hipMemsetAsync(cnt,  0, (size_t)N * 4, stream);
    hipMemsetAsync(wacc, 0, (size_t)N * 4, stream);
    hipMemsetAsync(svec, 0, 64 * 4, stream);

    int gridE = (E + 255) / 256;
    int gridN = (N + 255) / 256;

    count_kernel<<<gridE, 256, 0, stream>>>(ei, cnt, E);
    dinv_kernel<<<gridN, 256, 0, stream>>>(cnt, dinv, N);
    scan_kernel<<<1, 1024, 0, stream>>>(cnt, rowstart, cursor, N);
    scatter_kernel<<<gridE, 256, 0, stream>>>(ei, dinv, cursor, csr_src, wacc, E);

    int gridM = (N + MT - 1) / MT;
    gemm_g<<<gridM, 256, 0, stream>>>(x, W1, dinv, g, N);

    agg_kernel<<<2048, 256, 0, stream>>>(g, rowstart, csr_src, dinv, wacc, b1, svec, N);

    final_kernel<<<1, 64, 0, stream>>>(svec, W2, b2, Wl, bl, out, 1.0f / (float)N);
}

// Round 2
// 408.849 us; speedup vs baseline: 1.5136x; 1.5136x over previous
//
#include <hip/hip_runtime.h>
#include <hip/hip_bf16.h>
#include <math.h>

// ---------------------------------------------------------------------------
// GCN forward, algebraically collapsed:
//   h1 = relu( dinv[d]*(sum_{e:dst=d} g[src_e] + g[d]) + b1 ),  g = (x@W1)*dinv
//   pooled = (1/N) * (sum_n w[n]*h1[n]) @ W2 + b2,
//       w[n] = dinv[n]*(wacc[n] + dinv[n]),  wacc[n] = sum_{e:src=n} dinv[dst_e]
//   out = sigmoid(pooled @ Wl + bl)
// ---------------------------------------------------------------------------

#define F_IN 256
#define H 64

// ---- K1: in-degree count ---------------------------------------------------
__global__ void count_kernel(const int* __restrict__ ei, int* __restrict__ cnt, int E) {
    int e = blockIdx.x * 256 + threadIdx.x;
    if (e < E) atomicAdd(&cnt[ei[E + e]], 1);
}

// ---- K2a: dinv -------------------------------------------------------------
__global__ void dinv_kernel(const int* __restrict__ cnt, float* __restrict__ dinv, int N) {
    int n = blockIdx.x * 256 + threadIdx.x;
    if (n < N) dinv[n] = rsqrtf(1.0f + (float)cnt[n]);
}

// ---- K2b: multi-block exclusive scan (3 phases) ----------------------------
// 512 elements per block, 256 threads, 2 contiguous ints per thread.
#define SCAN_ELEMS 512

// phase A: per-block partial sums
__global__ __launch_bounds__(256) void scan_partial(const int* __restrict__ cnt,
                                                    int* __restrict__ bsum, int N) {
    int b = blockIdx.x, t = threadIdx.x;
    int i0 = b * SCAN_ELEMS + t * 2;
    int c0 = (i0     < N) ? cnt[i0]     : 0;
    int c1 = (i0 + 1 < N) ? cnt[i0 + 1] : 0;
    __shared__ int red[256];
    red[t] = c0 + c1;
    __syncthreads();
    #pragma unroll
    for (int off = 128; off >= 1; off >>= 1) {
        if (t < off) red[t] += red[t + off];
        __syncthreads();
    }
    if (t == 0) bsum[b] = red[0];
}

// phase B: single small block scans the NB block sums (NB <= 256), exclusive.
// Also writes rowstart[N] = total.
__global__ __launch_bounds__(256) void scan_bsum(int* __restrict__ bsum,
                                                 int* __restrict__ rowstart,
                                                 int NB, int N) {
    __shared__ int lds[256];
    int t = threadIdx.x;
    int v = (t < NB) ? bsum[t] : 0;
    lds[t] = v;
    __syncthreads();
    #pragma unroll
    for (int off = 1; off < 256; off <<= 1) {
        int u = (t >= off) ? lds[t - off] : 0;
        __syncthreads();
        lds[t] += u;
        __syncthreads();
    }
    if (t < NB) bsum[t] = lds[t] - v;      // exclusive
    if (t == 0) rowstart[N] = lds[255];    // grand total (lanes >= NB added 0)
}

// phase C: per-block local scan + block offset -> rowstart, cursor
__global__ __launch_bounds__(256) void scan_final(const int* __restrict__ cnt,
                                                  const int* __restrict__ bsum,
                                                  int* __restrict__ rowstart,
                                                  int* __restrict__ cursor, int N) {
    int b = blockIdx.x, t = threadIdx.x;
    int i0 = b * SCAN_ELEMS + t * 2;
    int c0 = (i0     < N) ? cnt[i0]     : 0;
    int c1 = (i0 + 1 < N) ? cnt[i0 + 1] : 0;
    int s = c0 + c1;
    __shared__ int lds[256];
    lds[t] = s;
    __syncthreads();
    #pragma unroll
    for (int off = 1; off < 256; off <<= 1) {
        int u = (t >= off) ? lds[t - off] : 0;
        __syncthreads();
        lds[t] += u;
        __syncthreads();
    }
    int pre = lds[t] - s + bsum[b];        // exclusive prefix for element i0
    if (i0 < N)     { rowstart[i0]     = pre;      cursor[i0]     = pre;      }
    if (i0 + 1 < N) { rowstart[i0 + 1] = pre + c0; cursor[i0 + 1] = pre + c0; }
}

// ---- K3: CSR scatter + wacc ------------------------------------------------
__global__ void scatter_kernel(const int* __restrict__ ei, const float* __restrict__ dinv,
                               int* __restrict__ cursor, int* __restrict__ csr_src,
                               float* __restrict__ wacc, int E) {
    int e = blockIdx.x * 256 + threadIdx.x;
    if (e < E) {
        int s = ei[e], d = ei[E + e];
        int pos = atomicAdd(&cursor[d], 1);
        csr_src[pos] = s;
        atomicAdd(&wacc[s], dinv[d]);
    }
}

// ---- K4: GEMM  g = (x @ W1) * dinv  ---------------------------------------
// 128x64 tile per block, 256 threads, 8x4 micro-tile, KT=32
#define MT 128
#define KT 32
__global__ __launch_bounds__(256) void gemm_g(const float* __restrict__ x,
                                              const float* __restrict__ W1,
                                              const float* __restrict__ dinv,
                                              float* __restrict__ g, int M) {
    __shared__ float As[KT][MT + 4];   // stored transposed; stride 132 floats (16B aligned)
    __shared__ float Bs[KT][H];
    int t = threadIdx.x;
    int rowbase = blockIdx.x * MT;
    int m0 = (t >> 4) * 8;
    int n0 = (t & 15) * 4;
    float acc[8][4] = {};
    for (int k0 = 0; k0 < F_IN; k0 += KT) {
        #pragma unroll
        for (int i = 0; i < 4; ++i) {          // stage A (transposed)
            int idx = t + i * 256;             // 0..1023
            int r  = idx >> 3;
            int kv = idx & 7;
            int row = rowbase + r;
            float4 v = make_float4(0.f, 0.f, 0.f, 0.f);
            if (row < M) v = *reinterpret_cast<const float4*>(&x[(size_t)row * F_IN + k0 + kv * 4]);
            As[kv * 4 + 0][r] = v.x; As[kv * 4 + 1][r] = v.y;
            As[kv * 4 + 2][r] = v.z; As[kv * 4 + 3][r] = v.w;
        }
        #pragma unroll
        for (int i = 0; i < 2; ++i) {          // stage B
            int idx = t + i * 256;             // 0..511
            int kk = idx >> 4;
            int cv = idx & 15;
            *reinterpret_cast<float4*>(&Bs[kk][cv * 4]) =
                *reinterpret_cast<const float4*>(&W1[(size_t)(k0 + kk) * H + cv * 4]);
        }
        __syncthreads();
        #pragma unroll
        for (int k = 0; k < KT; ++k) {
            float4 a0 = *reinterpret_cast<const float4*>(&As[k][m0]);
            float4 a1 = *reinterpret_cast<const float4*>(&As[k][m0 + 4]);
            float4 b  = *reinterpret_cast<const float4*>(&Bs[k][n0]);
            float am[8] = {a0.x, a0.y, a0.z, a0.w, a1.x, a1.y, a1.z, a1.w};
            float bn[4] = {b.x, b.y, b.z, b.w};
            #pragma unroll
            for (int mi = 0; mi < 8; ++mi)
                #pragma unroll
                for (int ni = 0; ni < 4; ++ni)
                    acc[mi][ni] += am[mi] * bn[ni];
        }
        __syncthreads();
    }
    #pragma unroll
    for (int mi = 0; mi < 8; ++mi) {
        int row = rowbase + m0 + mi;
        if (row < M) {
            float dv = dinv[row];
            float4 o = make_float4(acc[mi][0] * dv, acc[mi][1] * dv,
                                   acc[mi][2] * dv, acc[mi][3] * dv);
            *reinterpret_cast<float4*>(&g[(size_t)row * H + n0]) = o;
        }
    }
}

// ---- K6: per-node aggregation + relu + weighted reduction ------------------
__global__ __launch_bounds__(256) void agg_kernel(const float* __restrict__ g,
                                                  const int* __restrict__ rowstart,
                                                  const int* __restrict__ csr_src,
                                                  const float* __restrict__ dinv,
                                                  const float* __restrict__ wacc,
                                                  const float* __restrict__ b1,
                                                  float* __restrict__ svec, int N) {
    int lane = threadIdx.x & 63;
    int wIb  = threadIdx.x >> 6;
    int wave = blockIdx.x * 4 + wIb;
    int nWaves = gridDim.x * 4;
    float bb = b1[lane];
    float racc = 0.f;
    for (int n = wave; n < N; n += nWaves) {
        int js = rowstart[n], je = rowstart[n + 1];
        float s = 0.f;
        int j = js;
        for (; j + 3 < je; j += 4) {           // 4-way batched: break dependent-load chain
            int s0 = csr_src[j], s1 = csr_src[j + 1], s2 = csr_src[j + 2], s3 = csr_src[j + 3];
            float g0 = g[(size_t)s0 * H + lane];
            float g1 = g[(size_t)s1 * H + lane];
            float g2 = g[(size_t)s2 * H + lane];
            float g3 = g[(size_t)s3 * H + lane];
            s += (g0 + g1) + (g2 + g3);
        }
        for (; j < je; ++j) s += g[(size_t)csr_src[j] * H + lane];
        float dv = dinv[n];
        float h1 = dv * (s + g[(size_t)n * H + lane]) + bb;
        h1 = fmaxf(h1, 0.f);
        float wn = dv * (wacc[n] + dv);
        racc += wn * h1;
    }
    __shared__ float red[4][64];
    red[wIb][lane] = racc;
    __syncthreads();
    if (wIb == 0) {
        float v = red[0][lane] + red[1][lane] + red[2][lane] + red[3][lane];
        atomicAdd(&svec[lane], v);
    }
}

// ---- K7: final tiny head ---------------------------------------------------
__global__ void final_kernel(const float* __restrict__ svec,
                             const float* __restrict__ W2, const float* __restrict__ b2,
                             const float* __restrict__ Wl, const float* __restrict__ bl,
                             float* __restrict__ out, float invN) {
    __shared__ float pooled[64];
    __shared__ float sv[64];
    int t = threadIdx.x;   // 64 threads
    sv[t] = svec[t];
    __syncthreads();
    float acc = 0.f;
    for (int k = 0; k < 64; ++k) acc += sv[k] * W2[k * 64 + t];
    pooled[t] = acc * invN + b2[t];
    __syncthreads();
    if (t < 10) {
        float a = 0.f;
        for (int j = 0; j < 64; ++j) a += pooled[j] * Wl[j * 10 + t];
        a += bl[t];
        out[t] = 1.f / (1.f + expf(-a));
    }
}

// ---------------------------------------------------------------------------
extern "C" void kernel_launch(void* const* d_in, const int* in_sizes, int n_in,
                              void* d_out, int out_size, void* d_ws, size_t ws_size,
                              hipStream_t stream) {
    const float* x   = (const float*)d_in[0];
    const int*   ei  = (const int*)d_in[1];
    const float* W1  = (const float*)d_in[2];
    const float* b1  = (const float*)d_in[3];
    const float* W2  = (const float*)d_in[4];
    const float* b2  = (const float*)d_in[5];
    const float* Wl  = (const float*)d_in[6];
    const float* bl  = (const float*)d_in[7];
    float* out = (float*)d_out;

    const int N = in_sizes[0] / F_IN;
    const int E = in_sizes[1] / 2;

    // workspace carve-up (256B aligned)
    char* ws = (char*)d_ws;
    size_t off = 0;
    auto carve = [&](size_t bytes) -> char* {
        char* p = ws + off;
        off = (off + bytes + 255) & ~(size_t)255;
        return p;
    };
    int*   cnt      = (int*)  carve((size_t)N * 4);
    int*   rowstart = (int*)  carve((size_t)(N + 1) * 4);
    int*   cursor   = (int*)  carve((size_t)N * 4);
    float* dinv     = (float*)carve((size_t)N * 4);
    float* wacc     = (float*)carve((size_t)N * 4);
    float* svec     = (float*)carve(64 * 4);
    int*   bsum     = (int*)  carve(256 * 4);
    int*   csr_src  = (int*)  carve((size_t)E * 4);
    float* g        = (float*)carve((size_t)N * H * 4);
    (void)ws_size; (void)n_in; (void)out_size;

    hipMemsetAsync(cnt,  0, (size_t)N * 4, stream);
    hipMemsetAsync(wacc, 0, (size_t)N * 4, stream);
    hipMemsetAsync(svec, 0, 64 * 4, stream);

    int gridE = (E + 255) / 256;
    int gridN = (N + 255) / 256;
    int NB    = (N + SCAN_ELEMS - 1) / SCAN_ELEMS;   // 196 for N=100000 (must be <= 256)

    count_kernel<<<gridE, 256, 0, stream>>>(ei, cnt, E);
    dinv_kernel<<<gridN, 256, 0, stream>>>(cnt, dinv, N);
    scan_partial<<<NB, 256, 0, stream>>>(cnt, bsum, N);
    scan_bsum<<<1, 256, 0, stream>>>(bsum, rowstart, NB, N);
    scan_final<<<NB, 256, 0, stream>>>(cnt, bsum, rowstart, cursor, N);
    scatter_kernel<<<gridE, 256, 0, stream>>>(ei, dinv, cursor, csr_src, wacc, E);

    int gridM = (N + MT - 1) / MT;
    gemm_g<<<gridM, 256, 0, stream>>>(x, W1, dinv, g, N);

    agg_kernel<<<2048, 256, 0, stream>>>(g, rowstart, csr_src, dinv, wacc, b1, svec, N);

    final_kernel<<<1, 64, 0, stream>>>(svec, W2, b2, Wl, bl, out, 1.0f / (float)N);
}

// Round 3
// 299.614 us; speedup vs baseline: 2.0654x; 1.3646x over previous
//
#include <hip/hip_runtime.h>
#include <hip/hip_bf16.h>
#include <math.h>

// ---------------------------------------------------------------------------
// GCN forward, algebraically collapsed:
//   h1 = relu( dinv[d]*(sum_{e:dst=d} g[src_e] + g[d]) + b1 ),  g = (x@W1)*dinv
//   pooled = (1/N) * (sum_n w[n]*h1[n]) @ W2 + b2,
//       w[n] = dinv[n]*(wacc[n] + dinv[n]),  wacc[n] = sum_{e:src=n} dinv[dst_e]
//   out = sigmoid(pooled @ Wl + bl)
//
// CSR build is a 2-level bucket partition (bucket = dst>>8, 256 nodes each):
//   P1 hist -> P2 bucket scan -> P3 partition (LDS-staged, coalesced bursts)
//   -> P4 per-bucket local count/scan/dinv/rowstart/csr (+ wacc atomics)
// ---------------------------------------------------------------------------

#define F_IN 256
#define H 64
#define BSHIFT 8
#define NBUCK_MAX 512
#define P3_CH 8192

// ---- P1: bucket histogram --------------------------------------------------
__global__ __launch_bounds__(256) void hist_kernel(const int* __restrict__ ei,
                                                   int* __restrict__ bcnt,
                                                   int E, int nbuck) {
    __shared__ int h[NBUCK_MAX];
    for (int i = threadIdx.x; i < NBUCK_MAX; i += 256) h[i] = 0;
    __syncthreads();
    int stride = gridDim.x * 256;
    for (int e = blockIdx.x * 256 + threadIdx.x; e < E; e += stride)
        atomicAdd(&h[ei[E + e] >> BSHIFT], 1);
    __syncthreads();
    for (int b = threadIdx.x; b < nbuck; b += 256)
        if (h[b]) atomicAdd(&bcnt[b], h[b]);
}

// ---- P2: scan bucket counts (1 block) --------------------------------------
__global__ __launch_bounds__(512) void bscan_kernel(const int* __restrict__ bcnt,
                                                    int* __restrict__ bbase,
                                                    int* __restrict__ bcur,
                                                    int nbuck, int E) {
    __shared__ int lds[512];
    int t = threadIdx.x;
    int v = (t < nbuck) ? bcnt[t] : 0;
    lds[t] = v;
    __syncthreads();
    #pragma unroll
    for (int off = 1; off < 512; off <<= 1) {
        int u = (t >= off) ? lds[t - off] : 0;
        __syncthreads();
        lds[t] += u;
        __syncthreads();
    }
    if (t < nbuck) { bbase[t] = lds[t] - v; bcur[t] = lds[t] - v; }
    if (t == 0) bbase[nbuck] = E;
}

// ---- P3: partition edges into bucket regions (LDS staged, coalesced) -------
__global__ __launch_bounds__(512) void part_kernel(const int* __restrict__ ei,
                                                   int* __restrict__ bcur,
                                                   int2* __restrict__ recs,
                                                   int E, int nbuck) {
    __shared__ int hist[NBUCK_MAX], segb[NBUCK_MAX], blkb[NBUCK_MAX], ctr[NBUCK_MAX];
    __shared__ int2 stage[P3_CH];
    int t = threadIdx.x;
    int base = blockIdx.x * P3_CH;
    int cnt = E - base; if (cnt > P3_CH) cnt = P3_CH;
    for (int i = t; i < NBUCK_MAX; i += 512) { hist[i] = 0; ctr[i] = 0; }
    __syncthreads();
    for (int i = t; i < cnt; i += 512)
        atomicAdd(&hist[ei[E + base + i] >> BSHIFT], 1);
    __syncthreads();
    // exclusive scan of hist -> segb
    int v = hist[t];
    segb[t] = v;
    __syncthreads();
    #pragma unroll
    for (int off = 1; off < 512; off <<= 1) {
        int u = (t >= off) ? segb[t - off] : 0;
        __syncthreads();
        segb[t] += u;
        __syncthreads();
    }
    int excl = segb[t] - v;
    __syncthreads();
    segb[t] = excl;
    if (t < nbuck && v) blkb[t] = atomicAdd(&bcur[t], v);
    __syncthreads();
    // stage sorted-by-bucket in LDS
    for (int i = t; i < cnt; i += 512) {
        int s = ei[base + i], d = ei[E + base + i];
        int b = d >> BSHIFT;
        int r = atomicAdd(&ctr[b], 1);
        stage[segb[b] + r] = make_int2(s, d);
    }
    __syncthreads();
    // burst copy to global bucket regions
    for (int i = t; i < cnt; i += 512) {
        int2 rc = stage[i];
        int b = rc.y >> BSHIFT;
        recs[blkb[b] + (i - segb[b])] = rc;
    }
}

// ---- P4: per-bucket local CSR build + dinv + rowstart + wacc ---------------
__global__ __launch_bounds__(256) void build_kernel(const int2* __restrict__ recs,
                                                    const int* __restrict__ bbase,
                                                    float* __restrict__ dinv,
                                                    int* __restrict__ rowstart,
                                                    int* __restrict__ csr_src,
                                                    float* __restrict__ wacc,
                                                    int N, int E) {
    __shared__ int cnt[256], lbase[256], ctr[256];
    __shared__ float dloc[256];
    int b = blockIdx.x, t = threadIdx.x;
    int e0 = bbase[b], e1 = bbase[b + 1];
    cnt[t] = 0; ctr[t] = 0;
    __syncthreads();
    for (int i = e0 + t; i < e1; i += 256)
        atomicAdd(&cnt[recs[i].y & 255], 1);
    __syncthreads();
    int v = cnt[t];
    lbase[t] = v;
    __syncthreads();
    #pragma unroll
    for (int off = 1; off < 256; off <<= 1) {
        int u = (t >= off) ? lbase[t - off] : 0;
        __syncthreads();
        lbase[t] += u;
        __syncthreads();
    }
    int excl = lbase[t] - v;
    __syncthreads();
    lbase[t] = excl;
    float dv = rsqrtf(1.0f + (float)v);
    dloc[t] = dv;
    int n = (b << BSHIFT) + t;
    if (n < N) { dinv[n] = dv; rowstart[n] = e0 + excl; }
    if (b == 0 && t == 0) rowstart[N] = E;
    __syncthreads();
    for (int i = e0 + t; i < e1; i += 256) {
        int2 rc = recs[i];
        int dl = rc.y & 255;
        int r = atomicAdd(&ctr[dl], 1);
        csr_src[e0 + lbase[dl] + r] = rc.x;
        atomicAdd(&wacc[rc.x], dloc[dl]);
    }
}

// ---- K4: GEMM  g = (x @ W1) * dinv  ---------------------------------------
#define MT 128
#define KT 32
__global__ __launch_bounds__(256) void gemm_g(const float* __restrict__ x,
                                              const float* __restrict__ W1,
                                              const float* __restrict__ dinv,
                                              float* __restrict__ g, int M) {
    __shared__ float As[KT][MT + 4];
    __shared__ float Bs[KT][H];
    int t = threadIdx.x;
    int rowbase = blockIdx.x * MT;
    int m0 = (t >> 4) * 8;
    int n0 = (t & 15) * 4;
    float acc[8][4] = {};
    for (int k0 = 0; k0 < F_IN; k0 += KT) {
        #pragma unroll
        for (int i = 0; i < 4; ++i) {
            int idx = t + i * 256;
            int r  = idx >> 3;
            int kv = idx & 7;
            int row = rowbase + r;
            float4 v = make_float4(0.f, 0.f, 0.f, 0.f);
            if (row < M) v = *reinterpret_cast<const float4*>(&x[(size_t)row * F_IN + k0 + kv * 4]);
            As[kv * 4 + 0][r] = v.x; As[kv * 4 + 1][r] = v.y;
            As[kv * 4 + 2][r] = v.z; As[kv * 4 + 3][r] = v.w;
        }
        #pragma unroll
        for (int i = 0; i < 2; ++i) {
            int idx = t + i * 256;
            int kk = idx >> 4;
            int cv = idx & 15;
            *reinterpret_cast<float4*>(&Bs[kk][cv * 4]) =
                *reinterpret_cast<const float4*>(&W1[(size_t)(k0 + kk) * H + cv * 4]);
        }
        __syncthreads();
        #pragma unroll
        for (int k = 0; k < KT; ++k) {
            float4 a0 = *reinterpret_cast<const float4*>(&As[k][m0]);
            float4 a1 = *reinterpret_cast<const float4*>(&As[k][m0 + 4]);
            float4 bv = *reinterpret_cast<const float4*>(&Bs[k][n0]);
            float am[8] = {a0.x, a0.y, a0.z, a0.w, a1.x, a1.y, a1.z, a1.w};
            float bn[4] = {bv.x, bv.y, bv.z, bv.w};
            #pragma unroll
            for (int mi = 0; mi < 8; ++mi)
                #pragma unroll
                for (int ni = 0; ni < 4; ++ni)
                    acc[mi][ni] += am[mi] * bn[ni];
        }
        __syncthreads();
    }
    #pragma unroll
    for (int mi = 0; mi < 8; ++mi) {
        int row = rowbase + m0 + mi;
        if (row < M) {
            float dv = dinv[row];
            float4 o = make_float4(acc[mi][0] * dv, acc[mi][1] * dv,
                                   acc[mi][2] * dv, acc[mi][3] * dv);
            *reinterpret_cast<float4*>(&g[(size_t)row * H + n0]) = o;
        }
    }
}

// ---- K6: per-node aggregation + relu + weighted reduction ------------------
__global__ __launch_bounds__(256) void agg_kernel(const float* __restrict__ g,
                                                  const int* __restrict__ rowstart,
                                                  const int* __restrict__ csr_src,
                                                  const float* __restrict__ dinv,
                                                  const float* __restrict__ wacc,
                                                  const float* __restrict__ b1,
                                                  float* __restrict__ svec, int N) {
    int lane = threadIdx.x & 63;
    int wIb  = threadIdx.x >> 6;
    int wave = blockIdx.x * 4 + wIb;
    int nWaves = gridDim.x * 4;
    float bb = b1[lane];
    float racc = 0.f;
    for (int n = wave; n < N; n += nWaves) {
        int js = rowstart[n], je = rowstart[n + 1];
        float s = 0.f;
        int j = js;
        for (; j + 3 < je; j += 4) {
            int s0 = csr_src[j], s1 = csr_src[j + 1], s2 = csr_src[j + 2], s3 = csr_src[j + 3];
            float g0 = g[(size_t)s0 * H + lane];
            float g1 = g[(size_t)s1 * H + lane];
            float g2 = g[(size_t)s2 * H + lane];
            float g3 = g[(size_t)s3 * H + lane];
            s += (g0 + g1) + (g2 + g3);
        }
        for (; j < je; ++j) s += g[(size_t)csr_src[j] * H + lane];
        float dv = dinv[n];
        float h1 = dv * (s + g[(size_t)n * H + lane]) + bb;
        h1 = fmaxf(h1, 0.f);
        float wn = dv * (wacc[n] + dv);
        racc += wn * h1;
    }
    __shared__ float red[4][64];
    red[wIb][lane] = racc;
    __syncthreads();
    if (wIb == 0) {
        float vv = red[0][lane] + red[1][lane] + red[2][lane] + red[3][lane];
        atomicAdd(&svec[lane], vv);
    }
}

// ---- K7: final tiny head ---------------------------------------------------
__global__ void final_kernel(const float* __restrict__ svec,
                             const float* __restrict__ W2, const float* __restrict__ b2,
                             const float* __restrict__ Wl, const float* __restrict__ bl,
                             float* __restrict__ out, float invN) {
    __shared__ float pooled[64];
    __shared__ float sv[64];
    int t = threadIdx.x;
    sv[t] = svec[t];
    __syncthreads();
    float acc = 0.f;
    for (int k = 0; k < 64; ++k) acc += sv[k] * W2[k * 64 + t];
    pooled[t] = acc * invN + b2[t];
    __syncthreads();
    if (t < 10) {
        float a = 0.f;
        for (int j = 0; j < 64; ++j) a += pooled[j] * Wl[j * 10 + t];
        a += bl[t];
        out[t] = 1.f / (1.f + expf(-a));
    }
}

// ---------------------------------------------------------------------------
extern "C" void kernel_launch(void* const* d_in, const int* in_sizes, int n_in,
                              void* d_out, int out_size, void* d_ws, size_t ws_size,
                              hipStream_t stream) {
    const float* x   = (const float*)d_in[0];
    const int*   ei  = (const int*)d_in[1];
    const float* W1  = (const float*)d_in[2];
    const float* b1  = (const float*)d_in[3];
    const float* W2  = (const float*)d_in[4];
    const float* b2  = (const float*)d_in[5];
    const float* Wl  = (const float*)d_in[6];
    const float* bl  = (const float*)d_in[7];
    float* out = (float*)d_out;

    const int N = in_sizes[0] / F_IN;
    const int E = in_sizes[1] / 2;
    const int nbuck = (N + 255) >> BSHIFT;   // 391 for N=100000 (must be <= NBUCK_MAX)

    // workspace carve-up (256B aligned)
    char* ws = (char*)d_ws;
    size_t off = 0;
    auto carve = [&](size_t bytes) -> char* {
        char* p = ws + off;
        off = (off + bytes + 255) & ~(size_t)255;
        return p;
    };
    int*   bcnt     = (int*)  carve((size_t)NBUCK_MAX * 4);
    int*   bbase    = (int*)  carve((size_t)(NBUCK_MAX + 1) * 4);
    int*   bcur     = (int*)  carve((size_t)NBUCK_MAX * 4);
    int*   rowstart = (int*)  carve((size_t)(N + 1) * 4);
    float* dinv     = (float*)carve((size_t)N * 4);
    float* wacc     = (float*)carve((size_t)N * 4);
    float* svec     = (float*)carve(64 * 4);
    int*   csr_src  = (int*)  carve((size_t)E * 4);
    // recs (E*8 bytes) overlays g (N*64*4 bytes): recs dead before gemm writes g
    size_t ovl = (size_t)E * 8;
    size_t gsz = (size_t)N * H * 4;
    char*  ovlp     = carve(ovl > gsz ? ovl : gsz);
    int2*  recs     = (int2*)ovlp;
    float* g        = (float*)ovlp;
    (void)ws_size; (void)n_in; (void)out_size;

    hipMemsetAsync(bcnt, 0, (size_t)NBUCK_MAX * 4, stream);
    hipMemsetAsync(wacc, 0, (size_t)N * 4, stream);
    hipMemsetAsync(svec, 0, 64 * 4, stream);

    hist_kernel<<<nbuck, 256, 0, stream>>>(ei, bcnt, E, nbuck);
    bscan_kernel<<<1, 512, 0, stream>>>(bcnt, bbase, bcur, nbuck, E);
    int gridP3 = (E + P3_CH - 1) / P3_CH;
    part_kernel<<<gridP3, 512, 0, stream>>>(ei, bcur, recs, E, nbuck);
    build_kernel<<<nbuck, 256, 0, stream>>>(recs, bbase, dinv, rowstart, csr_src, wacc, N, E);

    int gridM = (N + MT - 1) / MT;
    gemm_g<<<gridM, 256, 0, stream>>>(x, W1, dinv, g, N);

    agg_kernel<<<2048, 256, 0, stream>>>(g, rowstart, csr_src, dinv, wacc, b1, svec, N);

    final_kernel<<<1, 64, 0, stream>>>(svec, W2, b2, Wl, bl, out, 1.0f / (float)N);
}

// Round 4
// 293.986 us; speedup vs baseline: 2.1050x; 1.0191x over previous
//
#include <hip/hip_runtime.h>
#include <hip/hip_bf16.h>
#include <math.h>

// ---------------------------------------------------------------------------
// GCN forward, algebraically collapsed:
//   h1 = relu( dinv[d]*(sum_{e:dst=d} g[src_e] + g[d]) + b1 ),  g = (x@W1)*dinv
//   pooled = (1/N) * (sum_n w[n]*h1[n]) @ W2 + b2,
//       w[n] = dinv[n]*(wacc[n] + dinv[n]),  wacc[n] = sum_{e:src=n} dinv[dst_e]
//   out = sigmoid(pooled @ Wl + bl)
//
// g is stored bf16 (halves the edge-gather traffic; error ~1e-6 at output).
// CSR build: 2-level bucket partition (bucket = dst>>8).
// ---------------------------------------------------------------------------

#define F_IN 256
#define H 64
#define BSHIFT 8
#define NBUCK_MAX 512
#define P3_CH 8192

__device__ __forceinline__ ushort f2bf(float f) {
    uint b = __float_as_uint(f);
    return (ushort)((b + 0x7FFFu + ((b >> 16) & 1u)) >> 16);   // RNE
}
__device__ __forceinline__ float bf2f(ushort u) {
    return __uint_as_float(((uint)u) << 16);
}

// ---- P1: bucket histogram --------------------------------------------------
__global__ __launch_bounds__(256) void hist_kernel(const int* __restrict__ ei,
                                                   int* __restrict__ bcnt,
                                                   int E, int nbuck) {
    __shared__ int h[NBUCK_MAX];
    for (int i = threadIdx.x; i < NBUCK_MAX; i += 256) h[i] = 0;
    __syncthreads();
    int stride = gridDim.x * 256;
    for (int e = blockIdx.x * 256 + threadIdx.x; e < E; e += stride)
        atomicAdd(&h[ei[E + e] >> BSHIFT], 1);
    __syncthreads();
    for (int b = threadIdx.x; b < nbuck; b += 256)
        if (h[b]) atomicAdd(&bcnt[b], h[b]);
}

// ---- P2: scan bucket counts (1 block) --------------------------------------
__global__ __launch_bounds__(512) void bscan_kernel(const int* __restrict__ bcnt,
                                                    int* __restrict__ bbase,
                                                    int* __restrict__ bcur,
                                                    int nbuck, int E) {
    __shared__ int lds[512];
    int t = threadIdx.x;
    int v = (t < nbuck) ? bcnt[t] : 0;
    lds[t] = v;
    __syncthreads();
    #pragma unroll
    for (int off = 1; off < 512; off <<= 1) {
        int u = (t >= off) ? lds[t - off] : 0;
        __syncthreads();
        lds[t] += u;
        __syncthreads();
    }
    if (t < nbuck) { bbase[t] = lds[t] - v; bcur[t] = lds[t] - v; }
    if (t == 0) bbase[nbuck] = E;
}

// ---- P3: partition edges into bucket regions (LDS staged, coalesced) -------
__global__ __launch_bounds__(512) void part_kernel(const int* __restrict__ ei,
                                                   int* __restrict__ bcur,
                                                   int2* __restrict__ recs,
                                                   int E, int nbuck) {
    __shared__ int hist[NBUCK_MAX], segb[NBUCK_MAX], blkb[NBUCK_MAX], ctr[NBUCK_MAX];
    __shared__ int2 stage[P3_CH];
    int t = threadIdx.x;
    int base = blockIdx.x * P3_CH;
    int cnt = E - base; if (cnt > P3_CH) cnt = P3_CH;
    for (int i = t; i < NBUCK_MAX; i += 512) { hist[i] = 0; ctr[i] = 0; }
    __syncthreads();
    for (int i = t; i < cnt; i += 512)
        atomicAdd(&hist[ei[E + base + i] >> BSHIFT], 1);
    __syncthreads();
    int v = hist[t];
    segb[t] = v;
    __syncthreads();
    #pragma unroll
    for (int off = 1; off < 512; off <<= 1) {
        int u = (t >= off) ? segb[t - off] : 0;
        __syncthreads();
        segb[t] += u;
        __syncthreads();
    }
    int excl = segb[t] - v;
    __syncthreads();
    segb[t] = excl;
    if (t < nbuck && v) blkb[t] = atomicAdd(&bcur[t], v);
    __syncthreads();
    for (int i = t; i < cnt; i += 512) {
        int s = ei[base + i], d = ei[E + base + i];
        int b = d >> BSHIFT;
        int r = atomicAdd(&ctr[b], 1);
        stage[segb[b] + r] = make_int2(s, d);
    }
    __syncthreads();
    for (int i = t; i < cnt; i += 512) {
        int2 rc = stage[i];
        int b = rc.y >> BSHIFT;
        recs[blkb[b] + (i - segb[b])] = rc;
    }
}

// ---- P4: per-bucket local CSR build + dinv + rowstart + wacc ---------------
__global__ __launch_bounds__(256) void build_kernel(const int2* __restrict__ recs,
                                                    const int* __restrict__ bbase,
                                                    float* __restrict__ dinv,
                                                    int* __restrict__ rowstart,
                                                    int* __restrict__ csr_src,
                                                    float* __restrict__ wacc,
                                                    int N, int E) {
    __shared__ int cnt[256], lbase[256], ctr[256];
    __shared__ float dloc[256];
    int b = blockIdx.x, t = threadIdx.x;
    int e0 = bbase[b], e1 = bbase[b + 1];
    cnt[t] = 0; ctr[t] = 0;
    __syncthreads();
    for (int i = e0 + t; i < e1; i += 256)
        atomicAdd(&cnt[recs[i].y & 255], 1);
    __syncthreads();
    int v = cnt[t];
    lbase[t] = v;
    __syncthreads();
    #pragma unroll
    for (int off = 1; off < 256; off <<= 1) {
        int u = (t >= off) ? lbase[t - off] : 0;
        __syncthreads();
        lbase[t] += u;
        __syncthreads();
    }
    int excl = lbase[t] - v;
    __syncthreads();
    lbase[t] = excl;
    float dv = rsqrtf(1.0f + (float)v);
    dloc[t] = dv;
    int n = (b << BSHIFT) + t;
    if (n < N) { dinv[n] = dv; rowstart[n] = e0 + excl; }
    if (b == 0 && t == 0) rowstart[N] = E;
    __syncthreads();
    for (int i = e0 + t; i < e1; i += 256) {
        int2 rc = recs[i];
        int dl = rc.y & 255;
        int r = atomicAdd(&ctr[dl], 1);
        csr_src[e0 + lbase[dl] + r] = rc.x;
        atomicAdd(&wacc[rc.x], dloc[dl]);
    }
}

// ---- K4: GEMM  g = (x @ W1) * dinv  (bf16 output) --------------------------
#define MT 128
#define KT 32
__global__ __launch_bounds__(256) void gemm_g(const float* __restrict__ x,
                                              const float* __restrict__ W1,
                                              const float* __restrict__ dinv,
                                              ushort* __restrict__ gb, int M) {
    __shared__ float As[KT][MT + 4];
    __shared__ float Bs[KT][H];
    int t = threadIdx.x;
    int rowbase = blockIdx.x * MT;
    int m0 = (t >> 4) * 8;
    int n0 = (t & 15) * 4;
    float acc[8][4] = {};
    for (int k0 = 0; k0 < F_IN; k0 += KT) {
        #pragma unroll
        for (int i = 0; i < 4; ++i) {
            int idx = t + i * 256;
            int r  = idx >> 3;
            int kv = idx & 7;
            int row = rowbase + r;
            float4 v = make_float4(0.f, 0.f, 0.f, 0.f);
            if (row < M) v = *reinterpret_cast<const float4*>(&x[(size_t)row * F_IN + k0 + kv * 4]);
            As[kv * 4 + 0][r] = v.x; As[kv * 4 + 1][r] = v.y;
            As[kv * 4 + 2][r] = v.z; As[kv * 4 + 3][r] = v.w;
        }
        #pragma unroll
        for (int i = 0; i < 2; ++i) {
            int idx = t + i * 256;
            int kk = idx >> 4;
            int cv = idx & 15;
            *reinterpret_cast<float4*>(&Bs[kk][cv * 4]) =
                *reinterpret_cast<const float4*>(&W1[(size_t)(k0 + kk) * H + cv * 4]);
        }
        __syncthreads();
        #pragma unroll
        for (int k = 0; k < KT; ++k) {
            float4 a0 = *reinterpret_cast<const float4*>(&As[k][m0]);
            float4 a1 = *reinterpret_cast<const float4*>(&As[k][m0 + 4]);
            float4 bv = *reinterpret_cast<const float4*>(&Bs[k][n0]);
            float am[8] = {a0.x, a0.y, a0.z, a0.w, a1.x, a1.y, a1.z, a1.w};
            float bn[4] = {bv.x, bv.y, bv.z, bv.w};
            #pragma unroll
            for (int mi = 0; mi < 8; ++mi)
                #pragma unroll
                for (int ni = 0; ni < 4; ++ni)
                    acc[mi][ni] += am[mi] * bn[ni];
        }
        __syncthreads();
    }
    #pragma unroll
    for (int mi = 0; mi < 8; ++mi) {
        int row = rowbase + m0 + mi;
        if (row < M) {
            float dv = dinv[row];
            ushort4 o;
            o.x = f2bf(acc[mi][0] * dv);
            o.y = f2bf(acc[mi][1] * dv);
            o.z = f2bf(acc[mi][2] * dv);
            o.w = f2bf(acc[mi][3] * dv);
            *reinterpret_cast<ushort4*>(&gb[(size_t)row * H + n0]) = o;
        }
    }
}

// ---- K6: per-node aggregation + relu + weighted reduction (bf16 gather) ----
__global__ __launch_bounds__(256) void agg_kernel(const ushort* __restrict__ gb,
                                                  const int* __restrict__ rowstart,
                                                  const int* __restrict__ csr_src,
                                                  const float* __restrict__ dinv,
                                                  const float* __restrict__ wacc,
                                                  const float* __restrict__ b1,
                                                  float* __restrict__ svec, int N) {
    int lane = threadIdx.x & 63;
    int wIb  = threadIdx.x >> 6;
    int wave = blockIdx.x * 4 + wIb;
    int nWaves = gridDim.x * 4;
    float bb = b1[lane];
    float racc = 0.f;
    for (int n = wave; n < N; n += nWaves) {
        int js = rowstart[n], je = rowstart[n + 1];
        float s = 0.f;
        int j = js;
        for (; j + 7 < je; j += 8) {            // 8 independent rows in flight
            int i0 = csr_src[j],     i1 = csr_src[j + 1];
            int i2 = csr_src[j + 2], i3 = csr_src[j + 3];
            int i4 = csr_src[j + 4], i5 = csr_src[j + 5];
            int i6 = csr_src[j + 6], i7 = csr_src[j + 7];
            float g0 = bf2f(gb[(size_t)i0 * H + lane]);
            float g1 = bf2f(gb[(size_t)i1 * H + lane]);
            float g2 = bf2f(gb[(size_t)i2 * H + lane]);
            float g3 = bf2f(gb[(size_t)i3 * H + lane]);
            float g4 = bf2f(gb[(size_t)i4 * H + lane]);
            float g5 = bf2f(gb[(size_t)i5 * H + lane]);
            float g6 = bf2f(gb[(size_t)i6 * H + lane]);
            float g7 = bf2f(gb[(size_t)i7 * H + lane]);
            s += ((g0 + g1) + (g2 + g3)) + ((g4 + g5) + (g6 + g7));
        }
        for (; j < je; ++j) s += bf2f(gb[(size_t)csr_src[j] * H + lane]);
        float dv = dinv[n];
        float h1 = dv * (s + bf2f(gb[(size_t)n * H + lane])) + bb;
        h1 = fmaxf(h1, 0.f);
        float wn = dv * (wacc[n] + dv);
        racc += wn * h1;
    }
    __shared__ float red[4][64];
    red[wIb][lane] = racc;
    __syncthreads();
    if (wIb == 0) {
        float vv = red[0][lane] + red[1][lane] + red[2][lane] + red[3][lane];
        atomicAdd(&svec[lane], vv);
    }
}

// ---- K7: final tiny head ---------------------------------------------------
__global__ void final_kernel(const float* __restrict__ svec,
                             const float* __restrict__ W2, const float* __restrict__ b2,
                             const float* __restrict__ Wl, const float* __restrict__ bl,
                             float* __restrict__ out, float invN) {
    __shared__ float pooled[64];
    __shared__ float sv[64];
    int t = threadIdx.x;
    sv[t] = svec[t];
    __syncthreads();
    float acc = 0.f;
    for (int k = 0; k < 64; ++k) acc += sv[k] * W2[k * 64 + t];
    pooled[t] = acc * invN + b2[t];
    __syncthreads();
    if (t < 10) {
        float a = 0.f;
        for (int j = 0; j < 64; ++j) a += pooled[j] * Wl[j * 10 + t];
        a += bl[t];
        out[t] = 1.f / (1.f + expf(-a));
    }
}

// ---------------------------------------------------------------------------
extern "C" void kernel_launch(void* const* d_in, const int* in_sizes, int n_in,
                              void* d_out, int out_size, void* d_ws, size_t ws_size,
                              hipStream_t stream) {
    const float* x   = (const float*)d_in[0];
    const int*   ei  = (const int*)d_in[1];
    const float* W1  = (const float*)d_in[2];
    const float* b1  = (const float*)d_in[3];
    const float* W2  = (const float*)d_in[4];
    const float* b2  = (const float*)d_in[5];
    const float* Wl  = (const float*)d_in[6];
    const float* bl  = (const float*)d_in[7];
    float* out = (float*)d_out;

    const int N = in_sizes[0] / F_IN;
    const int E = in_sizes[1] / 2;
    const int nbuck = (N + 255) >> BSHIFT;

    char* ws = (char*)d_ws;
    size_t off = 0;
    auto carve = [&](size_t bytes) -> char* {
        char* p = ws + off;
        off = (off + bytes + 255) & ~(size_t)255;
        return p;
    };
    int*   bcnt     = (int*)  carve((size_t)NBUCK_MAX * 4);
    int*   bbase    = (int*)  carve((size_t)(NBUCK_MAX + 1) * 4);
    int*   bcur     = (int*)  carve((size_t)NBUCK_MAX * 4);
    int*   rowstart = (int*)  carve((size_t)(N + 1) * 4);
    float* dinv     = (float*)carve((size_t)N * 4);
    float* wacc     = (float*)carve((size_t)N * 4);
    float* svec     = (float*)carve(64 * 4);
    int*   csr_src  = (int*)  carve((size_t)E * 4);
    // recs (E*8 B) overlays gb (N*64*2 B): recs dead before gemm writes gb
    size_t ovl = (size_t)E * 8;
    size_t gsz = (size_t)N * H * 2;
    char*  ovlp     = carve(ovl > gsz ? ovl : gsz);
    int2*  recs     = (int2*)ovlp;
    ushort* gb      = (ushort*)ovlp;
    (void)ws_size; (void)n_in; (void)out_size;

    hipMemsetAsync(bcnt, 0, (size_t)NBUCK_MAX * 4, stream);
    hipMemsetAsync(wacc, 0, (size_t)N * 4, stream);
    hipMemsetAsync(svec, 0, 64 * 4, stream);

    hist_kernel<<<nbuck, 256, 0, stream>>>(ei, bcnt, E, nbuck);
    bscan_kernel<<<1, 512, 0, stream>>>(bcnt, bbase, bcur, nbuck, E);
    int gridP3 = (E + P3_CH - 1) / P3_CH;
    part_kernel<<<gridP3, 512, 0, stream>>>(ei, bcur, recs, E, nbuck);
    build_kernel<<<nbuck, 256, 0, stream>>>(recs, bbase, dinv, rowstart, csr_src, wacc, N, E);

    int gridM = (N + MT - 1) / MT;
    gemm_g<<<gridM, 256, 0, stream>>>(x, W1, dinv, gb, N);

    agg_kernel<<<2048, 256, 0, stream>>>(gb, rowstart, csr_src, dinv, wacc, b1, svec, N);

    final_kernel<<<1, 64, 0, stream>>>(svec, W2, b2, Wl, bl, out, 1.0f / (float)N);
}

// Round 5
// 286.754 us; speedup vs baseline: 2.1581x; 1.0252x over previous
//
#include <hip/hip_runtime.h>
#include <hip/hip_bf16.h>
#include <math.h>

// ---------------------------------------------------------------------------
// GCN forward, algebraically collapsed:
//   h1 = relu( dinv[d]*(sum_{e:dst=d} g[src_e] + g[d]) + b1 ),  g = (x@W1)*dinv
//   pooled = (1/N) * (sum_n w[n]*h1[n]) @ W2 + b2,
//       w[n] = dinv[n]*(wacc[n] + dinv[n]),  wacc[n] = sum_{e:src=n} dinv[dst_e]
//   out = sigmoid(pooled @ Wl + bl)
//
// g stored bf16. Edges partitioned into 128-dst buckets; within each bucket
// sorted by (dst&3, src>>9) so the agg phase's gathers sweep src-space in
// loose global synchrony -> L2-resident random reads + streamed fills.
// ---------------------------------------------------------------------------

#define F_IN 256
#define H 64
#define BSHIFT 7
#define BSZ 128
#define NBUCK_MAX 1024
#define P3_CH 8192

__device__ __forceinline__ ushort f2bf(float f) {
    uint b = __float_as_uint(f);
    return (ushort)((b + 0x7FFFu + ((b >> 16) & 1u)) >> 16);   // RNE
}
__device__ __forceinline__ float bf2f(ushort u) {
    return __uint_as_float(((uint)u) << 16);
}

// ---- P1: bucket histogram (bucket = dst>>7) --------------------------------
__global__ __launch_bounds__(256) void hist_kernel(const int* __restrict__ ei,
                                                   int* __restrict__ bcnt,
                                                   int E, int nbuck) {
    __shared__ int h[NBUCK_MAX];
    for (int i = threadIdx.x; i < NBUCK_MAX; i += 256) h[i] = 0;
    __syncthreads();
    int stride = gridDim.x * 256;
    for (int e = blockIdx.x * 256 + threadIdx.x; e < E; e += stride)
        atomicAdd(&h[ei[E + e] >> BSHIFT], 1);
    __syncthreads();
    for (int b = threadIdx.x; b < nbuck; b += 256)
        if (h[b]) atomicAdd(&bcnt[b], h[b]);
}

// ---- P2: scan bucket counts (1 block, 1024 thr) ----------------------------
__global__ __launch_bounds__(1024) void bscan_kernel(const int* __restrict__ bcnt,
                                                     int* __restrict__ bbase,
                                                     int* __restrict__ bcur,
                                                     int nbuck, int E) {
    __shared__ int lds[1024];
    int t = threadIdx.x;
    int v = (t < nbuck) ? bcnt[t] : 0;
    lds[t] = v;
    __syncthreads();
    #pragma unroll
    for (int off = 1; off < 1024; off <<= 1) {
        int u = (t >= off) ? lds[t - off] : 0;
        __syncthreads();
        lds[t] += u;
        __syncthreads();
    }
    if (t < nbuck) { bbase[t] = lds[t] - v; bcur[t] = lds[t] - v; }
    if (t == 0) bbase[nbuck] = E;
}

// ---- P3: partition edges into bucket regions (LDS staged, coalesced) -------
__global__ __launch_bounds__(512) void part_kernel(const int* __restrict__ ei,
                                                   int* __restrict__ bcur,
                                                   int2* __restrict__ recs,
                                                   int E) {
    __shared__ int hist[NBUCK_MAX], segb[NBUCK_MAX], blkb[NBUCK_MAX], ctr[NBUCK_MAX];
    __shared__ int scanbuf[512];
    __shared__ int2 stage[P3_CH];
    int t = threadIdx.x;
    int base = blockIdx.x * P3_CH;
    int cnt = E - base; if (cnt > P3_CH) cnt = P3_CH;
    for (int i = t; i < NBUCK_MAX; i += 512) { hist[i] = 0; ctr[i] = 0; }
    __syncthreads();
    for (int i = t; i < cnt; i += 512)
        atomicAdd(&hist[ei[E + base + i] >> BSHIFT], 1);
    __syncthreads();
    int v0 = hist[2 * t], v1 = hist[2 * t + 1];
    int s = v0 + v1;
    scanbuf[t] = s;
    __syncthreads();
    #pragma unroll
    for (int off = 1; off < 512; off <<= 1) {
        int u = (t >= off) ? scanbuf[t - off] : 0;
        __syncthreads();
        scanbuf[t] += u;
        __syncthreads();
    }
    int excl = scanbuf[t] - s;
    segb[2 * t] = excl;
    segb[2 * t + 1] = excl + v0;
    if (v0) blkb[2 * t]     = atomicAdd(&bcur[2 * t],     v0);
    if (v1) blkb[2 * t + 1] = atomicAdd(&bcur[2 * t + 1], v1);
    __syncthreads();
    for (int i = t; i < cnt; i += 512) {
        int sN = ei[base + i], d = ei[E + base + i];
        int b = d >> BSHIFT;
        int r = atomicAdd(&ctr[b], 1);
        stage[segb[b] + r] = make_int2(sN, d);
    }
    __syncthreads();
    for (int i = t; i < cnt; i += 512) {
        int2 rc = stage[i];
        int b = rc.y >> BSHIFT;
        recs[blkb[b] + (i - segb[b])] = rc;
    }
}

// ---- P4: per-bucket counting-sort by (dst&3, src>>9) + dinv + wacc ---------
__global__ __launch_bounds__(256) void build_kernel(const int2* __restrict__ recs,
                                                    const int* __restrict__ bbase,
                                                    float* __restrict__ dinv,
                                                    int* __restrict__ sedge,
                                                    int* __restrict__ qbase,
                                                    float* __restrict__ wacc,
                                                    int N, int NSB) {
    __shared__ int cnt[BSZ];
    __shared__ int bh[NBUCK_MAX];     // 4*NSB used (<=1024)
    __shared__ int bbl[NBUCK_MAX];
    __shared__ int bctr[NBUCK_MAX];
    __shared__ int scanbuf[256];
    __shared__ float dloc[BSZ];
    int b = blockIdx.x, t = threadIdx.x;
    int e0 = bbase[b], e1 = bbase[b + 1];
    if (t < BSZ) cnt[t] = 0;
    for (int i = t; i < NBUCK_MAX; i += 256) { bh[i] = 0; bctr[i] = 0; }
    __syncthreads();
    for (int i = e0 + t; i < e1; i += 256) {
        int2 rc = recs[i];
        int dl = rc.y & (BSZ - 1);
        atomicAdd(&cnt[dl], 1);
        atomicAdd(&bh[(dl & 3) * NSB + (rc.x >> 9)], 1);
    }
    __syncthreads();
    // scan bh over 4*NSB (padded to 1024), 4 bins per thread
    int b0 = bh[4 * t], b1 = bh[4 * t + 1], b2 = bh[4 * t + 2], b3 = bh[4 * t + 3];
    int s = b0 + b1 + b2 + b3;
    scanbuf[t] = s;
    __syncthreads();
    #pragma unroll
    for (int off = 1; off < 256; off <<= 1) {
        int u = (t >= off) ? scanbuf[t - off] : 0;
        __syncthreads();
        scanbuf[t] += u;
        __syncthreads();
    }
    int excl = scanbuf[t] - s;
    bbl[4 * t] = excl;
    bbl[4 * t + 1] = excl + b0;
    bbl[4 * t + 2] = excl + b0 + b1;
    bbl[4 * t + 3] = excl + b0 + b1 + b2;
    __syncthreads();
    if (t < 4) qbase[b * 4 + t] = bbl[t * NSB];
    if (t < BSZ) {
        float dv = rsqrtf(1.0f + (float)cnt[t]);
        dloc[t] = dv;
        int n = (b << BSHIFT) + t;
        if (n < N) dinv[n] = dv;
    }
    __syncthreads();
    for (int i = e0 + t; i < e1; i += 256) {
        int2 rc = recs[i];
        int dl = rc.y & (BSZ - 1);
        int bin = (dl & 3) * NSB + (rc.x >> 9);
        int pos = atomicAdd(&bctr[bin], 1);
        sedge[e0 + bbl[bin] + pos] = (rc.x << BSHIFT) | dl;
        atomicAdd(&wacc[rc.x], dloc[dl]);
    }
}

// ---- K4: GEMM  g = (x @ W1) * dinv  (bf16 output) --------------------------
#define MT 128
#define KT 32
__global__ __launch_bounds__(256) void gemm_g(const float* __restrict__ x,
                                              const float* __restrict__ W1,
                                              const float* __restrict__ dinv,
                                              ushort* __restrict__ gb, int M) {
    __shared__ float As[KT][MT + 4];
    __shared__ float Bs[KT][H];
    int t = threadIdx.x;
    int rowbase = blockIdx.x * MT;
    int m0 = (t >> 4) * 8;
    int n0 = (t & 15) * 4;
    float acc[8][4] = {};
    for (int k0 = 0; k0 < F_IN; k0 += KT) {
        #pragma unroll
        for (int i = 0; i < 4; ++i) {
            int idx = t + i * 256;
            int r  = idx >> 3;
            int kv = idx & 7;
            int row = rowbase + r;
            float4 v = make_float4(0.f, 0.f, 0.f, 0.f);
            if (row < M) v = *reinterpret_cast<const float4*>(&x[(size_t)row * F_IN + k0 + kv * 4]);
            As[kv * 4 + 0][r] = v.x; As[kv * 4 + 1][r] = v.y;
            As[kv * 4 + 2][r] = v.z; As[kv * 4 + 3][r] = v.w;
        }
        #pragma unroll
        for (int i = 0; i < 2; ++i) {
            int idx = t + i * 256;
            int kk = idx >> 4;
            int cv = idx & 15;
            *reinterpret_cast<float4*>(&Bs[kk][cv * 4]) =
                *reinterpret_cast<const float4*>(&W1[(size_t)(k0 + kk) * H + cv * 4]);
        }
        __syncthreads();
        #pragma unroll
        for (int k = 0; k < KT; ++k) {
            float4 a0 = *reinterpret_cast<const float4*>(&As[k][m0]);
            float4 a1 = *reinterpret_cast<const float4*>(&As[k][m0 + 4]);
            float4 bv = *reinterpret_cast<const float4*>(&Bs[k][n0]);
            float am[8] = {a0.x, a0.y, a0.z, a0.w, a1.x, a1.y, a1.z, a1.w};
            float bn[4] = {bv.x, bv.y, bv.z, bv.w};
            #pragma unroll
            for (int mi = 0; mi < 8; ++mi)
                #pragma unroll
                for (int ni = 0; ni < 4; ++ni)
                    acc[mi][ni] += am[mi] * bn[ni];
        }
        __syncthreads();
    }
    #pragma unroll
    for (int mi = 0; mi < 8; ++mi) {
        int row = rowbase + m0 + mi;
        if (row < M) {
            float dv = dinv[row];
            ushort4 o;
            o.x = f2bf(acc[mi][0] * dv);
            o.y = f2bf(acc[mi][1] * dv);
            o.z = f2bf(acc[mi][2] * dv);
            o.w = f2bf(acc[mi][3] * dv);
            *reinterpret_cast<ushort4*>(&gb[(size_t)row * H + n0]) = o;
        }
    }
}

// ---- K6: bucket-local LDS accumulation + relu + weighted reduction ---------
__global__ __launch_bounds__(256) void agg_kernel(const ushort* __restrict__ gb,
                                                  const int* __restrict__ bbase,
                                                  const int* __restrict__ qbase,
                                                  const int* __restrict__ sedge,
                                                  const float* __restrict__ dinv,
                                                  const float* __restrict__ wacc,
                                                  const float* __restrict__ b1,
                                                  float* __restrict__ svec, int N) {
    __shared__ float acc[BSZ][H];            // 32 KB
    __shared__ float red[4][64];
    int t = threadIdx.x;
    int lane = t & 63;
    int w = t >> 6;
    int b = blockIdx.x;
    float* af = &acc[0][0];
    for (int i = t; i < BSZ * H / 4; i += 256)
        reinterpret_cast<float4*>(af)[i] = make_float4(0.f, 0.f, 0.f, 0.f);
    __syncthreads();
    int e0 = bbase[b];
    int m  = bbase[b + 1] - e0;
    int qs = qbase[b * 4 + w];
    int qe = (w < 3) ? qbase[b * 4 + w + 1] : m;
    const int* sp = sedge + e0;
    int j = qs;
    for (; j + 7 < qe; j += 8) {
        int p0 = sp[j],     p1 = sp[j + 1], p2 = sp[j + 2], p3 = sp[j + 3];
        int p4 = sp[j + 4], p5 = sp[j + 5], p6 = sp[j + 6], p7 = sp[j + 7];
        float g0 = bf2f(gb[(size_t)((unsigned)p0 >> BSHIFT) * H + lane]);
        float g1 = bf2f(gb[(size_t)((unsigned)p1 >> BSHIFT) * H + lane]);
        float g2 = bf2f(gb[(size_t)((unsigned)p2 >> BSHIFT) * H + lane]);
        float g3 = bf2f(gb[(size_t)((unsigned)p3 >> BSHIFT) * H + lane]);
        float g4 = bf2f(gb[(size_t)((unsigned)p4 >> BSHIFT) * H + lane]);
        float g5 = bf2f(gb[(size_t)((unsigned)p5 >> BSHIFT) * H + lane]);
        float g6 = bf2f(gb[(size_t)((unsigned)p6 >> BSHIFT) * H + lane]);
        float g7 = bf2f(gb[(size_t)((unsigned)p7 >> BSHIFT) * H + lane]);
        acc[p0 & (BSZ - 1)][lane] += g0;
        acc[p1 & (BSZ - 1)][lane] += g1;
        acc[p2 & (BSZ - 1)][lane] += g2;
        acc[p3 & (BSZ - 1)][lane] += g3;
        acc[p4 & (BSZ - 1)][lane] += g4;
        acc[p5 & (BSZ - 1)][lane] += g5;
        acc[p6 & (BSZ - 1)][lane] += g6;
        acc[p7 & (BSZ - 1)][lane] += g7;
    }
    for (; j < qe; ++j) {
        int p = sp[j];
        acc[p & (BSZ - 1)][lane] += bf2f(gb[(size_t)((unsigned)p >> BSHIFT) * H + lane]);
    }
    __syncthreads();
    float bb = b1[lane];
    float racc = 0.f;
    #pragma unroll 4
    for (int r = 0; r < 32; ++r) {
        int dl = w * 32 + r;
        int n = (b << BSHIFT) + dl;
        if (n < N) {
            float dv = dinv[n];
            float a = acc[dl][lane] + bf2f(gb[(size_t)n * H + lane]);
            float h1 = fmaxf(dv * a + bb, 0.f);
            racc += (dv * (wacc[n] + dv)) * h1;
        }
    }
    red[w][lane] = racc;
    __syncthreads();
    if (w == 0) {
        float vv = red[0][lane] + red[1][lane] + red[2][lane] + red[3][lane];
        atomicAdd(&svec[lane], vv);
    }
}

// ---- K7: final tiny head ---------------------------------------------------
__global__ void final_kernel(const float* __restrict__ svec,
                             const float* __restrict__ W2, const float* __restrict__ b2,
                             const float* __restrict__ Wl, const float* __restrict__ bl,
                             float* __restrict__ out, float invN) {
    __shared__ float pooled[64];
    __shared__ float sv[64];
    int t = threadIdx.x;
    sv[t] = svec[t];
    __syncthreads();
    float acc = 0.f;
    for (int k = 0; k < 64; ++k) acc += sv[k] * W2[k * 64 + t];
    pooled[t] = acc * invN + b2[t];
    __syncthreads();
    if (t < 10) {
        float a = 0.f;
        for (int j = 0; j < 64; ++j) a += pooled[j] * Wl[j * 10 + t];
        a += bl[t];
        out[t] = 1.f / (1.f + expf(-a));
    }
}

// ---------------------------------------------------------------------------
extern "C" void kernel_launch(void* const* d_in, const int* in_sizes, int n_in,
                              void* d_out, int out_size, void* d_ws, size_t ws_size,
                              hipStream_t stream) {
    const float* x   = (const float*)d_in[0];
    const int*   ei  = (const int*)d_in[1];
    const float* W1  = (const float*)d_in[2];
    const float* b1  = (const float*)d_in[3];
    const float* W2  = (const float*)d_in[4];
    const float* b2  = (const float*)d_in[5];
    const float* Wl  = (const float*)d_in[6];
    const float* bl  = (const float*)d_in[7];
    float* out = (float*)d_out;

    const int N = in_sizes[0] / F_IN;
    const int E = in_sizes[1] / 2;
    const int nbuck = (N + BSZ - 1) >> BSHIFT;       // 782 for N=100000
    const int NSB   = (N + 511) >> 9;                // 196 src bins

    char* ws = (char*)d_ws;
    size_t off = 0;
    auto carve = [&](size_t bytes) -> char* {
        char* p = ws + off;
        off = (off + bytes + 255) & ~(size_t)255;
        return p;
    };
    int*   bcnt     = (int*)  carve((size_t)NBUCK_MAX * 4);
    int*   bbase    = (int*)  carve((size_t)(NBUCK_MAX + 1) * 4);
    int*   bcur     = (int*)  carve((size_t)NBUCK_MAX * 4);
    int*   qbase    = (int*)  carve((size_t)nbuck * 4 * 4);
    float* dinv     = (float*)carve((size_t)N * 4);
    float* wacc     = (float*)carve((size_t)N * 4);
    float* svec     = (float*)carve(64 * 4);
    int*   sedge    = (int*)  carve((size_t)E * 4);
    // recs (E*8 B) overlays gb (N*64*2 B): recs dead before gemm writes gb
    size_t ovl = (size_t)E * 8;
    size_t gsz = (size_t)N * H * 2;
    char*  ovlp     = carve(ovl > gsz ? ovl : gsz);
    int2*  recs     = (int2*)ovlp;
    ushort* gb      = (ushort*)ovlp;
    (void)ws_size; (void)n_in; (void)out_size;

    hipMemsetAsync(bcnt, 0, (size_t)NBUCK_MAX * 4, stream);
    hipMemsetAsync(wacc, 0, (size_t)N * 4, stream);
    hipMemsetAsync(svec, 0, 64 * 4, stream);

    hist_kernel<<<nbuck, 256, 0, stream>>>(ei, bcnt, E, nbuck);
    bscan_kernel<<<1, 1024, 0, stream>>>(bcnt, bbase, bcur, nbuck, E);
    int gridP3 = (E + P3_CH - 1) / P3_CH;
    part_kernel<<<gridP3, 512, 0, stream>>>(ei, bcur, recs, E);
    build_kernel<<<nbuck, 256, 0, stream>>>(recs, bbase, dinv, sedge, qbase, wacc, N, NSB);

    int gridM = (N + MT - 1) / MT;
    gemm_g<<<gridM, 256, 0, stream>>>(x, W1, dinv, gb, N);

    agg_kernel<<<nbuck, 256, 0, stream>>>(gb, bbase, qbase, sedge, dinv, wacc, b1, svec, N);

    final_kernel<<<1, 64, 0, stream>>>(svec, W2, b2, Wl, bl, out, 1.0f / (float)N);
}